// Round 1
// 143.983 us; speedup vs baseline: 1.0447x; 1.0447x over previous
//
#include <hip/hip_runtime.h>

#define THREADS 256
#define RPB 512   // rows per block; 2 rows per thread (tid, tid+256)

typedef float v2f __attribute__((ext_vector_type(2)));

// Force a wave-uniform value into an SGPR (valid because weights are uniform).
__device__ __forceinline__ float uni(float v) {
    return __int_as_float(__builtin_amdgcn_readfirstlane(__float_as_int(v)));
}

__device__ __forceinline__ v2f vsplat(float s) { v2f r; r.x = s; r.y = s; return r; }

// packed fma with wave-uniform scalar weight broadcast -> v_pk_fma_f32
__device__ __forceinline__ v2f vfma2(v2f a, float w, v2f acc) {
    return __builtin_elementwise_fma(a, vsplat(w), acc);
}

// tanh(x) = 1 - 2/(1 + exp(2x)); exp(2x) = exp2(x * 2*log2(e)); packed except trans ops
__device__ __forceinline__ v2f vtanh(v2f x) {
    v2f xs = x * vsplat(2.885390081777927f);
    v2f e;
    e.x = __builtin_amdgcn_exp2f(xs.x);
    e.y = __builtin_amdgcn_exp2f(xs.y);
    v2f r;
    r.x = __builtin_amdgcn_rcpf(e.x + 1.0f);
    r.y = __builtin_amdgcn_rcpf(e.y + 1.0f);
    return __builtin_elementwise_fma(vsplat(-2.0f), r, vsplat(1.0f));
}

__global__ __launch_bounds__(THREADS)
void recpolicy_kernel(const float* __restrict__ x,
                      const float* __restrict__ Wih_up,
                      const float* __restrict__ Whh_up,
                      const float* __restrict__ bih_up,
                      const float* __restrict__ bhh_up,
                      const float* __restrict__ W1,
                      const float* __restrict__ b1,
                      const float* __restrict__ W2,
                      const float* __restrict__ b2,
                      const float* __restrict__ Wih_dn,
                      const float* __restrict__ Whh_dn,
                      const float* __restrict__ bih_dn,
                      const float* __restrict__ bhh_dn,
                      const float* __restrict__ Wo,
                      const float* __restrict__ bo,
                      float* __restrict__ out)
{
    __shared__ float xs[RPB * 19];  // 512 rows x 18, padded to 19 (odd stride) = 38 KiB
    const int tid = threadIdx.x;
    const long long row0 = (long long)blockIdx.x * RPB;

    // ---- stage 512 rows x 18 f32 = 4608 float2, coalesced ----
    const float2* xg2 = (const float2*)(x + row0 * 18);
    #pragma unroll
    for (int k = 0; k < 18; ++k) {
        int idx2 = k * THREADS + tid;       // 0..4607
        float2 v = xg2[idx2];
        int r = idx2 / 9;                   // row (18 floats = 9 float2 per row)
        int c = (idx2 - r * 9) * 2;         // even column; pair never crosses a row
        xs[r * 19 + c]     = v.x;
        xs[r * 19 + c + 1] = v.y;
    }

    // ---- weights -> SGPRs (uniform) ----
    float wihu[8], whhu[16], bu[4];
    #pragma unroll
    for (int i = 0; i < 8; ++i) wihu[i] = uni(Wih_up[i]);
    #pragma unroll
    for (int i = 0; i < 16; ++i) whhu[i] = uni(Whh_up[i]);
    #pragma unroll
    for (int i = 0; i < 4; ++i) bu[i] = uni(bih_up[i] + bhh_up[i]);

    float w1[32], bb1[4], w2[16], bb2[4];
    #pragma unroll
    for (int i = 0; i < 32; ++i) w1[i] = uni(W1[i]);
    #pragma unroll
    for (int i = 0; i < 4; ++i) bb1[i] = uni(b1[i]);
    #pragma unroll
    for (int i = 0; i < 16; ++i) w2[i] = uni(W2[i]);
    #pragma unroll
    for (int i = 0; i < 4; ++i) bb2[i] = uni(b2[i]);

    float wihd[16], whhd[16], bd[4], wo[5], bO;
    #pragma unroll
    for (int i = 0; i < 16; ++i) wihd[i] = uni(Wih_dn[i]);
    #pragma unroll
    for (int i = 0; i < 16; ++i) whhd[i] = uni(Whh_dn[i]);
    #pragma unroll
    for (int i = 0; i < 4; ++i) bd[i] = uni(bih_dn[i] + bhh_dn[i]);
    #pragma unroll
    for (int i = 0; i < 5; ++i) wo[i] = uni(Wo[i]);
    bO = uni(bo[0]);

    __syncthreads();

    // ---- per-thread: two rows packed into v2f lanes ----
    const float* xr0 = &xs[tid * 19];
    const float* xr1 = &xs[(tid + 256) * 19];
    v2f obs[4], j[7], jd[7];
    #pragma unroll
    for (int i = 0; i < 4; ++i) { obs[i].x = xr0[i];      obs[i].y = xr1[i]; }
    #pragma unroll
    for (int i = 0; i < 7; ++i) { j[i].x  = xr0[4 + i];   j[i].y  = xr1[4 + i]; }
    #pragma unroll
    for (int i = 0; i < 7; ++i) { jd[i].x = xr0[11 + i];  jd[i].y = xr1[11 + i]; }

    // up scan: t = 6 .. 0 (reversed sequence), store h at each t
    v2f h[4], hup[7][4];
    #pragma unroll
    for (int i = 0; i < 4; ++i) h[i] = vsplat(0.0f);
    #pragma unroll
    for (int t = 6; t >= 0; --t) {
        v2f pre[4];
        #pragma unroll
        for (int i = 0; i < 4; ++i) {
            v2f a = vsplat(bu[i]);
            a = vfma2(j[t],  wihu[i * 2 + 0], a);
            a = vfma2(jd[t], wihu[i * 2 + 1], a);
            #pragma unroll
            for (int k = 0; k < 4; ++k) a = vfma2(h[k], whhu[i * 4 + k], a);
            pre[i] = a;
        }
        #pragma unroll
        for (int i = 0; i < 4; ++i) { h[i] = vtanh(pre[i]); hup[t][i] = h[i]; }
    }
    // h == h_last == hup[0]

    // head: h0 = tanh(W2 @ tanh(W1 @ [obs, h_last] + b1) + b2)
    v2f g[4];
    #pragma unroll
    for (int i = 0; i < 4; ++i) {
        v2f a = vsplat(bb1[i]);
        #pragma unroll
        for (int k = 0; k < 4; ++k) a = vfma2(obs[k], w1[i * 8 + k], a);
        #pragma unroll
        for (int k = 0; k < 4; ++k) a = vfma2(h[k],   w1[i * 8 + 4 + k], a);
        g[i] = vtanh(a);
    }
    #pragma unroll
    for (int i = 0; i < 4; ++i) {
        v2f a = vsplat(bb2[i]);
        #pragma unroll
        for (int k = 0; k < 4; ++k) a = vfma2(g[k], w2[i * 4 + k], a);
        h[i] = vtanh(a);
    }

    // down scan: t = 0 .. 6; act uses h BEFORE update
    v2f act[7];
    #pragma unroll
    for (int t = 0; t < 7; ++t) {
        v2f a = vsplat(bO);
        #pragma unroll
        for (int k = 0; k < 4; ++k) a = vfma2(h[k], wo[k], a);
        a = vfma2(j[t], wo[4], a);
        act[t] = a;
        v2f pre[4];
        #pragma unroll
        for (int i = 0; i < 4; ++i) {
            v2f s = vsplat(bd[i]);
            #pragma unroll
            for (int k = 0; k < 4; ++k) s = vfma2(hup[t][k], wihd[i * 4 + k], s);
            #pragma unroll
            for (int k = 0; k < 4; ++k) s = vfma2(h[k],      whhd[i * 4 + k], s);
            pre[i] = s;
        }
        #pragma unroll
        for (int i = 0; i < 4; ++i) h[i] = vtanh(pre[i]);  // t==6 update is dead-code-eliminated
    }

    // ---- stage output in LDS (reuse xs), then coalesced float2 store ----
    __syncthreads();
    float* os = xs;  // needs 512*7 = 3584 floats, fits in 512*19
    #pragma unroll
    for (int t = 0; t < 7; ++t) {
        os[tid * 7 + t]         = act[t].x;
        os[(tid + 256) * 7 + t] = act[t].y;
    }
    __syncthreads();
    const float2* os2 = (const float2*)os;          // 1792 float2
    float2* og2 = (float2*)(out + row0 * 7);        // 8B-aligned: row0*7*4 % 8 == 0
    #pragma unroll
    for (int k = 0; k < 7; ++k) og2[k * THREADS + tid] = os2[k * THREADS + tid];
}

extern "C" void kernel_launch(void* const* d_in, const int* in_sizes, int n_in,
                              void* d_out, int out_size, void* d_ws, size_t ws_size,
                              hipStream_t stream) {
    const float* x      = (const float*)d_in[0];
    const float* Wih_up = (const float*)d_in[1];
    const float* Whh_up = (const float*)d_in[2];
    const float* bih_up = (const float*)d_in[3];
    const float* bhh_up = (const float*)d_in[4];
    const float* W1     = (const float*)d_in[5];
    const float* b1     = (const float*)d_in[6];
    const float* W2     = (const float*)d_in[7];
    const float* b2     = (const float*)d_in[8];
    const float* Wih_dn = (const float*)d_in[9];
    const float* Whh_dn = (const float*)d_in[10];
    const float* bih_dn = (const float*)d_in[11];
    const float* bhh_dn = (const float*)d_in[12];
    const float* Wo     = (const float*)d_in[13];
    const float* bo     = (const float*)d_in[14];
    float* out = (float*)d_out;

    const int Btot = in_sizes[0] / 18;   // 1048576
    const int blocks = Btot / RPB;       // 2048

    recpolicy_kernel<<<blocks, THREADS, 0, stream>>>(
        x, Wih_up, Whh_up, bih_up, bhh_up, W1, b1, W2, b2,
        Wih_dn, Whh_dn, bih_dn, bhh_dn, Wo, bo, out);
}